// Round 5
// baseline (8097.059 us; speedup 1.0000x reference)
//
#include <hip/hip_runtime.h>

// Dims fixed by the reference
#define LAY 2
#define BATCH 64
#define TMAX 512
#define DIM 256
#define ROWS 16            // batch rows per workgroup
#define NWG  (BATCH / ROWS)
#define SLAB 65536         // BYTES per packed fp8 matrix (256x256)
#define AST  264           // LDS activation row stride (bytes, fp8); 264/4=66 -> conflict-free b64

typedef float floatx4 __attribute__((ext_vector_type(4)));
typedef long  longx2  __attribute__((ext_vector_type(2)));
#define MFMA_FP8 __builtin_amdgcn_mfma_f32_16x16x32_fp8_fp8

__device__ __forceinline__ unsigned int pk2(float a, float b) {
    // two fp32 -> two OCP e4m3 bytes in [7:0],[15:8]
    return (unsigned int)__builtin_amdgcn_cvt_pk_fp8_f32(a, b, 0, false);
}
__device__ __forceinline__ unsigned char f2q(float a) { return (unsigned char)(pk2(a, a) & 0xff); }
__device__ __forceinline__ float sigf(float x) { return 1.f / (1.f + __expf(-x)); }

// ---------------------------------------------------------------------------
// Weight prep: fp32 [L][256][256] ([k][n] row-major) -> e4m3 (x8 scale) packed
// so ONE wave dwordx4 load fetches TWO k-fragments of a 16-col tile:
//   byte addr = ((mat*16+nt)*4 + kp)*1024 + lane*16 + half*8 + j
//   holds 8*W[l][ k=(2kp+half)*32 + (lane>>4)*8 + j ][ n=nt*16 + (lane&15) ]
// One thread emits 2 bytes (one ushort). Also zeroes d_out.
// ---------------------------------------------------------------------------
__global__ void prep_weights(const float* __restrict__ Wz, const float* __restrict__ Wr,
                             const float* __restrict__ Uz, const float* __restrict__ Ur,
                             const float* __restrict__ Wh, const float* __restrict__ Uh,
                             unsigned short* __restrict__ wp, float* __restrict__ out) {
    int t = blockIdx.x * 256 + threadIdx.x;  // N = 786432/2 = 393216
    if (t == 0) out[0] = 0.f;
    int e    = t & 3;            // j pair: j0=2e, j1=2e+1
    int half = (t >> 2) & 1;
    int lane = (t >> 3) & 63;
    int kp   = (t >> 9) & 3;
    int nt   = (t >> 11) & 15;
    int mat  = t >> 15;          // l*6 + m
    int m = mat % 6;
    int l = mat / 6;
    const float* src;
    switch (m) {                 // 0=Wz 1=Wr 2=Uz 3=Ur 4=Wh 5=Uh
        case 0: src = Wz; break;
        case 1: src = Wr; break;
        case 2: src = Uz; break;
        case 3: src = Ur; break;
        case 4: src = Wh; break;
        default: src = Uh; break;
    }
    int n  = nt * 16 + (lane & 15);
    int k0 = (2 * kp + half) * 32 + (lane >> 4) * 8 + 2 * e;
    float w0 = src[(l << 16) + (k0 << 8) + n] * 8.f;        // x8: dodge e4m3 denormals
    float w1 = src[(l << 16) + ((k0 + 1) << 8) + n] * 8.f;  // undone by 0.125 post-acc
    wp[t] = (unsigned short)(pk2(w0, w1) & 0xffff);
}

// A[16x256] x W[256x32] into two 16x16 tiles: 8 dwordx4 weight loads (1KB/wave
// each, 2 k-frags per load), 16 fp8 MFMAs on two independent acc chains.
__device__ __forceinline__ void gemm2(const unsigned char* __restrict__ wl, int m,
                                      int nt0, int lane, const long* __restrict__ Af,
                                      floatx4& a0, floatx4& a1) {
    const longx2* p0 = (const longx2*)(wl + m * SLAB + nt0 * 4096) + lane;
    const longx2* p1 = p0 + 256;  // next 16-col tile (+4096 B)
    longx2 c0[4], c1[4];
#pragma unroll
    for (int kp = 0; kp < 4; ++kp) { c0[kp] = p0[kp * 64]; c1[kp] = p1[kp * 64]; }
#pragma unroll
    for (int kp = 0; kp < 4; ++kp) {
        a0 = MFMA_FP8(Af[2 * kp],     c0[kp].x, a0, 0, 0, 0);
        a1 = MFMA_FP8(Af[2 * kp],     c1[kp].x, a1, 0, 0, 0);
        a0 = MFMA_FP8(Af[2 * kp + 1], c0[kp].y, a0, 0, 0, 0);
        a1 = MFMA_FP8(Af[2 * kp + 1], c1[kp].y, a1, 0, 0, 0);
    }
}

// 4 WGs x 16 batch rows, 8 waves; wave w owns cols [32w,32w+32).
// S1 fp32 master lives in REGISTERS (lane owns its C-fragment cells);
// LDS holds fp8 activation copies + fp32 layer-1 state for the score.
__global__ __launch_bounds__(512, 2) void gru_main(const float* __restrict__ x,
                                                   const int* __restrict__ xlen,
                                                   const float* __restrict__ xlab,
                                                   const unsigned char* __restrict__ wp,
                                                   const float* __restrict__ Wo,
                                                   float* __restrict__ out) {
    __shared__ __align__(16) unsigned char s1q[LAY][ROWS][AST];  // S1 (fp8)
    __shared__ __align__(16) unsigned char xq[2][ROWS][AST];     // x_t double buffer (fp8)
    __shared__ __align__(16) unsigned char rsq[ROWS][AST];       // r*S1 (fp8)
    __shared__ __align__(16) float s1o[ROWS][264];               // layer-1 S1 fp32 (score)
    __shared__ float wo1s[DIM];

    const int tid  = threadIdx.x;
    const int wave = tid >> 6;
    const int lane = tid & 63;
    const int l15  = lane & 15;
    const int quad = lane >> 4;
    const int b0   = blockIdx.x * ROWS;

    // ---- init ----
    for (int i = tid; i < LAY * ROWS * AST; i += 512) ((unsigned char*)s1q)[i] = 0;
    if (tid < DIM) wo1s[tid] = Wo[2 * tid + 1];
#pragma unroll
    for (int rr = 0; rr < 2; ++rr) {  // x_0 -> xq[0]
        int r = wave * 2 + rr;
        float4 xv = *(const float4*)&x[((size_t)(b0 + r) * TMAX + 0) * DIM + lane * 4];
        unsigned int u = pk2(xv.x, xv.y) | (pk2(xv.z, xv.w) << 16);
        *(unsigned int*)&xq[0][r][lane * 4] = u;
    }
    const int   lenr = xlen[b0 + l15];
    const float labr = xlab[b0 + l15];
    int v = lenr;
#pragma unroll
    for (int o = 1; o < 16; o <<= 1) v = max(v, __shfl_xor(v, o));
    const int tmax = __builtin_amdgcn_readfirstlane(v);

    const int nt0  = wave * 2;
    const int colA = nt0 * 16 + l15;
    const int colB = colA + 16;
    const int rowb = quad * 4;
    float s1r[LAY][2][4];  // fp32 master S1: [layer][colTile][rowIdx]
#pragma unroll
    for (int l = 0; l < LAY; ++l)
#pragma unroll
        for (int c = 0; c < 2; ++c)
#pragma unroll
            for (int i = 0; i < 4; ++i) s1r[l][c][i] = 0.f;
    float accl = 0.f;
    __syncthreads();

    for (int t = 0; t < tmax; ++t) {
        const int buf = t & 1;
        for (int l = 0; l < LAY; ++l) {
            const unsigned char* Xs = (l == 0) ? &xq[buf][0][0] : &s1q[0][0][0];
            const unsigned char* Ss = &s1q[l][0][0];
            const unsigned char* wl = wp + (size_t)l * 6 * SLAB;

            // A-fragments (8B/lane, conflict-free b64 reads), reused across matmuls
            long xf[8], sf[8];
#pragma unroll
            for (int k = 0; k < 8; ++k) {
                xf[k] = *(const long*)&Xs[l15 * AST + k * 32 + quad * 8];
                sf[k] = *(const long*)&Ss[l15 * AST + k * 32 + quad * 8];
            }

            // ---- zr phase ----
            floatx4 za = {0.f, 0.f, 0.f, 0.f}, zb = za, ra = za, rb = za;
            gemm2(wl, 0, nt0, lane, xf, za, zb);  // X @ Wz
            gemm2(wl, 2, nt0, lane, sf, za, zb);  // S @ Uz
            gemm2(wl, 1, nt0, lane, xf, ra, rb);  // X @ Wr
            gemm2(wl, 3, nt0, lane, sf, ra, rb);  // S @ Ur

            float z0[4], z1[4];
#pragma unroll
            for (int i = 0; i < 4; ++i) {
                int row = rowb + i;
                z0[i] = sigf(0.125f * za[i]);
                z1[i] = sigf(0.125f * zb[i]);
                rsq[row][colA] = f2q(sigf(0.125f * ra[i]) * s1r[l][0][i]);
                rsq[row][colB] = f2q(sigf(0.125f * rb[i]) * s1r[l][1][i]);
            }
            __syncthreads();

            // ---- h phase ----
            long rf[8];
#pragma unroll
            for (int k = 0; k < 8; ++k)
                rf[k] = *(const long*)&rsq[l15 * AST + k * 32 + quad * 8 - l15 * AST + l15 * AST];
            floatx4 ha = {0.f, 0.f, 0.f, 0.f}, hb = ha;
            gemm2(wl, 4, nt0, lane, xf, ha, hb);  // X @ Wh
            gemm2(wl, 5, nt0, lane, rf, ha, hb);  // (r*S) @ Uh

            // prefetch x_{t+1} during layer 0 (writes the other xq buffer)
            if (l == 0 && t + 1 < tmax) {
#pragma unroll
                for (int rr = 0; rr < 2; ++rr) {
                    int r = wave * 2 + rr;
                    float4 xv = *(const float4*)&x[((size_t)(b0 + r) * TMAX + (t + 1)) * DIM + lane * 4];
                    unsigned int u = pk2(xv.x, xv.y) | (pk2(xv.z, xv.w) << 16);
                    *(unsigned int*)&xq[1 - buf][r][lane * 4] = u;
                }
            }

#pragma unroll
            for (int i = 0; i < 4; ++i) {
                int row = rowb + i;
                float h0 = tanhf(0.125f * ha[i]);
                float h1 = tanhf(0.125f * hb[i]);
                float hn0 = (1.f - z0[i]) * s1r[l][0][i] + z0[i] * h0;
                float hn1 = (1.f - z1[i]) * s1r[l][1][i] + z1[i] * h1;
                s1r[l][0][i] = hn0; s1q[l][row][colA] = f2q(hn0);
                s1r[l][1][i] = hn1; s1q[l][row][colB] = f2q(hn1);
                if (l == 1) { s1o[row][colA] = hn0; s1o[row][colB] = hn1; }
            }
            __syncthreads();
        }

        // ---- score (wave 0): fp32 path via s1o; safe until next layer-1 epilogue ----
        if (wave == 0) {
            const int row = l15, c0 = quad * 64;
            float p = 0.f;
#pragma unroll
            for (int u = 0; u < 64; u += 4) {
                float4 sv = *(const float4*)&s1o[row][c0 + u];
                float4 wv = *(const float4*)&wo1s[c0 + u];
                p = fmaf(sv.x, wv.x, p); p = fmaf(sv.y, wv.y, p);
                p = fmaf(sv.z, wv.z, p); p = fmaf(sv.w, wv.w, p);
            }
            p += __shfl_xor(p, 16);
            p += __shfl_xor(p, 32);
            if (lane < 16 && t < lenr) {
                float sc = sigf(p);
                float d = labr - sc;
                accl = fmaf(d, d, accl);
            }
        }
    }

    if (wave == 0) {
        accl += __shfl_xor(accl, 1);
        accl += __shfl_xor(accl, 2);
        accl += __shfl_xor(accl, 4);
        accl += __shfl_xor(accl, 8);
        if (lane == 0) atomicAdd(out, accl);
    }
}

extern "C" void kernel_launch(void* const* d_in, const int* in_sizes, int n_in,
                              void* d_out, int out_size, void* d_ws, size_t ws_size,
                              hipStream_t stream) {
    const float* x    = (const float*)d_in[0];
    const int*   xlen = (const int*)d_in[1];
    const float* xlab = (const float*)d_in[2];
    const float* Wz   = (const float*)d_in[3];
    const float* Uz   = (const float*)d_in[4];
    const float* Wr   = (const float*)d_in[5];
    const float* Ur   = (const float*)d_in[6];
    const float* Wh   = (const float*)d_in[7];
    const float* Uh   = (const float*)d_in[8];
    const float* Wo   = (const float*)d_in[9];
    float* out = (float*)d_out;
    unsigned short* wp16 = (unsigned short*)d_ws;  // 768 KB packed fp8 weights

    // ws is re-poisoned before every timed call -> rebuild packed weights every call.
    prep_weights<<<1536, 256, 0, stream>>>(Wz, Wr, Uz, Ur, Wh, Uh, wp16, out);
    gru_main<<<NWG, 512, 0, stream>>>(x, xlen, xlab, (const unsigned char*)wp16, Wo, out);
}